// Round 5
// baseline (75.340 us; speedup 1.0000x reference)
//
#include <hip/hip_runtime.h>

// Chamfer-style 3-level loss. P=128 polygons, N=128 pred pts, M=1024 gt pts.
// Round-8: single-dispatch via last-block-done reduction.
// Wall-time model (fits R0/R2/R4): ~40us unconditional harness ws-poison fill
// (268MB @84% HBM peak, present even when we never touch d_ws) + ~7-10us per
// dispatch launch gap + ~5us device work. Only remaining lever: dispatch
// count 2 -> 1. The init kernel existed only to zero out[0] for atomics;
// replaced by: per-block partials in a __device__ array (written before read,
// poison-immune), a module-load-zeroed ticket counter (self-resetting each
// exec -> graph-replay safe), last block does device-acquire fence, reduces
// 256 partials, plain-stores out[0], resets the counter.
// Release/acquire per guide G12/G16: __threadfence() before ticket atomicAdd
// (release), __threadfence() by all reader threads after flag broadcast
// (acquire). All 256 blocks are 1/CU co-resident -> no progress hazard.
// Per-point math and min-tree bit-identical to the absmax==0 version.
#define NPOLY 128
#define NPTS  128
#define NGT   1024
#define NBLK  256                // 1 block per CU
#define NTHR  768                // 12 waves; 24 groups of 32 lanes; 3 units

__device__ float g_part[NBLK];   // written-before-read each exec
__device__ int   g_ticket = 0;   // zeroed at module load; last block resets

__global__ __launch_bounds__(NTHR) void chamfer_one_kernel(
    const float* __restrict__ pred0,
    const float* __restrict__ pred1,
    const float* __restrict__ pred2,
    const float* __restrict__ gt,
    float* __restrict__ out) {
    __shared__ float wave_sums[12];
    __shared__ int   is_last;

    const int t = threadIdx.x;
    const int s = t & 31;        // gt slice within the 32-lane group
    const int g = t >> 5;        // group 0..23; 8 groups per unit

    // Unit = (level<<8) | (poly<<1) | half. 3 consecutive units per block.
    const int unit  = blockIdx.x * 3 + (g >> 3);
    const int half  = unit & 1;
    const int poly  = (unit >> 1) & (NPOLY - 1);
    const int level = unit >> 8;

    const float* pred = (level == 0) ? pred0 : ((level == 1) ? pred1 : pred2);
    const float  w    = (level == 0) ? 0.2f : ((level == 1) ? 0.3f : 0.5f);

    // gt point-pairs straight from global (1 MB total -> L2-resident).
    const float4* gsrc = (const float4*)(gt + (size_t)poly * (NGT * 2));

    // 16 independent global_load_dwordx4 in flight.
    float4 gq[16];
#pragma unroll
    for (int j = 0; j < 16; ++j) gq[j] = gsrc[(j << 5) + s];

    // This group's 8 pred points: coords [1:3] of [P,N,3]; 32-lane broadcast.
    float px[8], py[8], dmin[8];
#pragma unroll
    for (int p = 0; p < 8; ++p) {
        const float* pp =
            pred + ((size_t)poly * NPTS + half * 64 + (g & 7) * 8 + p) * 3 + 1;
        px[p]   = pp[0];
        py[p]   = pp[1];
        dmin[p] = 1e30f;
    }

    // 16 gt-pairs x 8 points per iteration; FP ops identical to the
    // absmax==0 version.
#pragma unroll
    for (int j = 0; j < 16; ++j) {
        float4 gq_j = gq[j];
#pragma unroll
        for (int p = 0; p < 8; ++p) {
            float dx0 = px[p] - gq_j.x, dy0 = py[p] - gq_j.y;
            float d0  = fmaf(dx0, dx0, dy0 * dy0);
            float dx1 = px[p] - gq_j.z, dy1 = py[p] - gq_j.w;
            float d1  = fmaf(dx1, dx1, dy1 * dy1);
            dmin[p] = fminf(dmin[p], fminf(d0, d1));
        }
    }

    // Min across the 32 slices (same butterfly as before).
#pragma unroll
    for (int o = 1; o <= 16; o <<= 1) {
#pragma unroll
        for (int p = 0; p < 8; ++p)
            dmin[p] = fminf(dmin[p], __shfl_xor(dmin[p], o));
    }

    // sqrt AFTER the full min (monotone -> same selection as reference).
    float d = 0.0f;
#pragma unroll
    for (int p = 0; p < 8; ++p) d += sqrtf(dmin[p]);

    // Partner group in this wave (same unit: 4 waves per unit, no straddle).
    d += __shfl_xor(d, 32);

    // Weight is uniform per wave (waves never straddle units).
    if ((t & 63) == 0) wave_sums[t >> 6] = d * w;
    __syncthreads();

    // Block partial -> device array; ticket to find the last block.
    if (t == 0) {
        float total = 0.0f;
#pragma unroll
        for (int i = 0; i < 12; ++i) total += wave_sums[i];
        g_part[blockIdx.x] = total * (1.0f / (3.0f * NPOLY * NPTS));
        __threadfence();                       // release partial
        int old = atomicAdd(&g_ticket, 1);     // device-scope ticket
        is_last = (old == NBLK - 1);
    }
    __syncthreads();

    if (is_last) {
        __threadfence();                       // acquire all partials
        float s2 = (t < NBLK) ? g_part[t] : 0.0f;
#pragma unroll
        for (int o = 1; o <= 32; o <<= 1) s2 += __shfl_xor(s2, o);
        if ((t & 63) == 0) wave_sums[t >> 6] = s2;
        __syncthreads();
        if (t == 0) {
            float tot = 0.0f;
#pragma unroll
            for (int i = 0; i < 12; ++i) tot += wave_sums[i];
            out[0] = tot;
            atomicExch(&g_ticket, 0);          // reset for next graph replay
        }
    }
}

extern "C" void kernel_launch(void* const* d_in, const int* in_sizes, int n_in,
                              void* d_out, int out_size, void* d_ws, size_t ws_size,
                              hipStream_t stream) {
    const float* pred0 = (const float*)d_in[0];
    const float* pred1 = (const float*)d_in[1];
    const float* pred2 = (const float*)d_in[2];
    const float* gt    = (const float*)d_in[3];
    float* out = (float*)d_out;

    chamfer_one_kernel<<<NBLK, NTHR, 0, stream>>>(pred0, pred1, pred2, gt, out);
}

// Round 6
// 66.821 us; speedup vs baseline: 1.1275x; 1.1275x over previous
//
#include <hip/hip_runtime.h>

// Chamfer-style 3-level loss. P=128 polygons, N=128 pred pts, M=1024 gt pts.
// Round-9: REVERT to the best measured configuration (R2/round-5 kernel,
// 67.97us, absmax 0.0). Session evidence that this is the practical floor:
//   - R0 (2 dispatches, LDS-staged)        = 68.2us
//   - R2 (2 dispatches, register-resident) = 68.0us  <- this kernel
//   - R4 (no-ws, init+main)                = 70.1us
//   - R5 (single dispatch, ticket+fence)   = 75.3us (ticket tail ~ +7us:
//     256 same-address device-scope atomics + fences + cross-XCD drain)
//   - R1 (cooperative launch)              = 121us   (uncapturable, host-serialized)
// Wall model fitting all rounds: ~40us unconditional harness ws-poison fill
// (268MB @ 84% HBM peak, present even with zero ws use) + ~20us harness
// reset-tail dispatches + ~5-8us our device work + ~2us gaps. Our portion is
// ~10% of the window; every structural variant moved the total by less than
// run noise (+/-2us). Remaining micro-opts (5-op -> 3-op inner loop, ~1us)
// are below noise and risk the absmax==0 bit-exactness.
#define NPOLY 128
#define NPTS  128
#define NGT   1024
#define NBLK  (3 * NPOLY * 2)   // 768 partials

__global__ __launch_bounds__(256) void chamfer_partial_kernel(
    const float* __restrict__ pred0,
    const float* __restrict__ pred1,
    const float* __restrict__ pred2,
    const float* __restrict__ gt,
    float* __restrict__ partial) {
    __shared__ float wave_sums[4];

    const int b     = blockIdx.x;
    const int half  = b & 1;
    const int poly  = (b >> 1) & (NPOLY - 1);
    const int level = b >> 8;         // 256 blocks per level

    const float* pred = (level == 0) ? pred0 : ((level == 1) ? pred1 : pred2);
    const float  w    = (level == 0) ? 0.2f : ((level == 1) ? 0.3f : 0.5f);

    const int t = threadIdx.x;
    const int s = t & 31;    // gt slice
    const int g = t >> 5;    // point-group 0..7

    // gt point-pairs straight from global (1 MB total -> L2-resident).
    // Slice s scans pairs j*32+s, same order as the original staged version.
    const float4* gsrc = (const float4*)(gt + (size_t)poly * (NGT * 2));

    // 16 independent global_load_dwordx4 in flight.
    float4 gq[16];
#pragma unroll
    for (int j = 0; j < 16; ++j) gq[j] = gsrc[(j << 5) + s];

    // This group's 8 pred points: coords [1:3] of [P,N,3]; 32-lane broadcast.
    float px[8], py[8], dmin[8];
#pragma unroll
    for (int p = 0; p < 8; ++p) {
        const float* pp =
            pred + ((size_t)poly * NPTS + half * 64 + g * 8 + p) * 3 + 1;
        px[p]   = pp[0];
        py[p]   = pp[1];
        dmin[p] = 1e30f;
    }

    // 16 gt-pairs x 8 points per iteration; FP ops identical to the
    // absmax==0 version.
#pragma unroll
    for (int j = 0; j < 16; ++j) {
        float4 gq_j = gq[j];
#pragma unroll
        for (int p = 0; p < 8; ++p) {
            float dx0 = px[p] - gq_j.x, dy0 = py[p] - gq_j.y;
            float d0  = fmaf(dx0, dx0, dy0 * dy0);
            float dx1 = px[p] - gq_j.z, dy1 = py[p] - gq_j.w;
            float d1  = fmaf(dx1, dx1, dy1 * dy1);
            dmin[p] = fminf(dmin[p], fminf(d0, d1));
        }
    }

    // Min across the 32 slices (same butterfly as before).
#pragma unroll
    for (int o = 1; o <= 16; o <<= 1) {
#pragma unroll
        for (int p = 0; p < 8; ++p)
            dmin[p] = fminf(dmin[p], __shfl_xor(dmin[p], o));
    }

    // sqrt AFTER the full min (monotone -> same selection as reference).
    float d = 0.0f;
#pragma unroll
    for (int p = 0; p < 8; ++p) d += sqrtf(dmin[p]);

    // Other point-group in this wave -> wave total (16 points).
    d += __shfl_xor(d, 32);

    if ((t & 63) == 0) wave_sums[t >> 6] = d;
    __syncthreads();

    if (t == 0) {
        float total = wave_sums[0] + wave_sums[1] + wave_sums[2] + wave_sums[3];
        partial[b] = total * (w * (1.0f / (3.0f * NPOLY * NPTS)));
    }
}

// Single block: sum 768 partials (L2-resident), plain store of the scalar.
__global__ __launch_bounds__(256) void reduce_partials_kernel(
    const float* __restrict__ partial, float* __restrict__ out) {
    __shared__ float wave_sums[4];
    const int t = threadIdx.x;
    float s = partial[t] + partial[t + 256] + partial[t + 512];
#pragma unroll
    for (int o = 1; o <= 32; o <<= 1) s += __shfl_xor(s, o);
    if ((t & 63) == 0) wave_sums[t >> 6] = s;
    __syncthreads();
    if (t == 0)
        out[0] = wave_sums[0] + wave_sums[1] + wave_sums[2] + wave_sums[3];
}

extern "C" void kernel_launch(void* const* d_in, const int* in_sizes, int n_in,
                              void* d_out, int out_size, void* d_ws, size_t ws_size,
                              hipStream_t stream) {
    const float* pred0 = (const float*)d_in[0];
    const float* pred1 = (const float*)d_in[1];
    const float* pred2 = (const float*)d_in[2];
    const float* gt    = (const float*)d_in[3];
    float* partial = (float*)d_ws;
    float* out     = (float*)d_out;

    chamfer_partial_kernel<<<NBLK, 256, 0, stream>>>(pred0, pred1, pred2, gt, partial);
    reduce_partials_kernel<<<1, 256, 0, stream>>>(partial, out);
}